// Round 3
// baseline (75.688 us; speedup 1.0000x reference)
//
#include <hip/hip_runtime.h>
#include <hip/hip_bf16.h>

// KAN conv: out[b,o,h,w] = sum_{j,k,l,m} phi(x[b,j,h+k,w+l])[m] * coeff[o,j,k,l,m]
// phi = uniform cubic B-spline basis (8 bases, knots = linspace(0,1,12)).
// R3: h-PAIR blocks (grid 31x16). phi rows h..h+3 staged once serve BOTH output
// rows (row r -> tap k=r for h0, k=r-1 for h1: exact partition, no waste).
// Wave = 2h x 64o x 16w -> B-frag reuse 4-8 MFMA (LDS reads /3). A-frags
// register-cached across r (k=r-1 reuse). B byte-addresses precomputed per lane.

typedef short v8s __attribute__((ext_vector_type(8)));
typedef float v4f __attribute__((ext_vector_type(4)));
typedef unsigned long long u64;
typedef u64 v2u64 __attribute__((ext_vector_type(2)));

#define B_N   16
#define CIN   64
#define COUT  64
#define H_IN  64
#define W_IN  64
#define NB    8
#define HO    62
#define WO    62
#define JC    8                    // Cin chunk size
#define NCH   (CIN / JC)           // 8 chunks
#define NROWS 4                    // phi rows staged (TH=2 outputs + K-1)
#define ROWSTRIDE 520              // ushorts per (r,j) row: 64*8 + 8 pad (bank stagger)
#define RSTRIDE   (JC * ROWSTRIDE) // ushorts per r-plane (8320 B)
#define ELEMS (NROWS * JC * W_IN)  // 2048 x-elements per chunk
#define EPT   (ELEMS / 256)        // 8 per thread

__device__ __forceinline__ ushort f2bf(float f) {
    // round-to-nearest-even fp32 -> bf16
    uint xu = __float_as_uint(f);
    return (ushort)((xu + 0x7fffu + ((xu >> 16) & 1u)) >> 16);
}

// Rearrange coeff [o][j][k][l][m] f32 -> bt[t=j*9+k*3+l][o][m] bf16 (576 KB)
__global__ void prep_coeff_kernel(const float* __restrict__ coeff, ushort* __restrict__ bt) {
    int n = blockIdx.x * 256 + threadIdx.x;
    if (n >= 576 * COUT * NB) return;
    int m = n & 7;
    int o = (n >> 3) & 63;
    int t = n >> 9;            // j*9 + k*3 + l
    int j = t / 9;
    int r9 = t - j * 9;
    float v = coeff[(((o * CIN + j) * 9 + r9) << 3) + m];
    bt[n] = f2bf(v);
}

template<bool USE_BT>
__global__ __launch_bounds__(256, 2) void kan_conv_kernel(
        const float* __restrict__ x, const ushort* __restrict__ cb,
        const float* __restrict__ coeff_f, float* __restrict__ out) {
    const int h0   = blockIdx.x * 2;   // output row pair base, 0..60
    const int b    = blockIdx.y;
    const int tid  = threadIdx.x;
    const int lane = tid & 63;
    const int wq   = tid >> 6;         // wave = w-quarter 0..3
    const int g    = lane >> 4;        // K-subgroup 0..3
    const int l15  = lane & 15;

    // phi_lds[r(4)][j(JC)][w(64)+pad][m(8)] bf16, padded rows = 33280 B
    __shared__ __align__(16) ushort phi_lds[NROWS * RSTRIDE];

    // per-lane constant addresses (combo c = s*4+g -> j_local=c/3, l=c%3)
    int baddr[6];   // LDS byte addr within r-plane 0
    int abase[6];   // byte offset into bt chunk base (k and ot added later)
    #pragma unroll
    for (int s = 0; s < 6; ++s) {
        int c   = s * 4 + g;
        int jl  = c / 3;
        int lc  = c - jl * 3;
        int bq  = wq * 16 + l15 + lc;
        bq = bq < 63 ? bq : 63;        // clamped lanes' outputs masked at store
        baddr[s] = (jl * ROWSTRIDE + bq * NB) * 2;
        abase[s] = ((jl * 9 + lc) * COUT + l15) * 16;
    }

    v4f acc0[4], acc1[4];
    #pragma unroll
    for (int ot = 0; ot < 4; ++ot) {
        acc0[ot] = (v4f){0.f, 0.f, 0.f, 0.f};
        acc1[ot] = (v4f){0.f, 0.f, 0.f, 0.f};
    }

    // prologue: load x for chunk 0
    float xv[EPT];
    #pragma unroll
    for (int it = 0; it < EPT; ++it) {
        int n = it * 256 + tid;
        int r = n >> 9;
        int j = (n >> 6) & (JC - 1);
        int w = n & (W_IN - 1);
        xv[it] = x[((b * CIN + j) * H_IN + (h0 + r)) * W_IN + w];
    }

    for (int jc = 0; jc < NCH; ++jc) {
        // ---- compute phi + single 16B LDS write per element ----
        #pragma unroll
        for (int it = 0; it < EPT; ++it) {
            int n = it * 256 + tid;
            int r = n >> 9;
            int j = (n >> 6) & (JC - 1);
            int w = n & (W_IN - 1);
            float s  = xv[it] * 11.0f;
            int i0 = (int)s;
            i0 = i0 < 0 ? 0 : (i0 > 10 ? 10 : i0);
            float u  = s - (float)i0;
            float um = 1.0f - u;
            float u2 = u * u, u3 = u2 * u;
            const float inv6 = 1.0f / 6.0f;
            float n0 = um * um * um * inv6;
            float n1 = (3.0f * u3 - 6.0f * u2 + 4.0f) * inv6;
            float n2 = (-3.0f * u3 + 3.0f * u2 + 3.0f * u + 1.0f) * inv6;
            float n3 = u3 * inv6;
            u64 V = (u64)f2bf(n0) | ((u64)f2bf(n1) << 16)
                  | ((u64)f2bf(n2) << 32) | ((u64)f2bf(n3) << 48);
            int bi = i0 - 3;   // first active basis index, in [-3, 7]
            u64 lo = bi < 0 ? (V >> (uint)(-16 * bi))
                   : bi < 4 ? (V << (uint)(16 * bi)) : 0ull;
            u64 hi = bi <= 0 ? 0ull
                   : bi < 4 ? (V >> (uint)(64 - 16 * bi))
                   : (V << (uint)(16 * bi - 64));
            v2u64 pk; pk[0] = lo; pk[1] = hi;
            *reinterpret_cast<v2u64*>(&phi_lds[(r * JC + j) * ROWSTRIDE + w * NB]) = pk;
        }
        // ---- prefetch x for chunk jc+1 (rides under GEMM) ----
        if (jc + 1 < NCH) {
            int j0n = (jc + 1) * JC;
            #pragma unroll
            for (int it = 0; it < EPT; ++it) {
                int n = it * 256 + tid;
                int r = n >> 9;
                int j = (n >> 6) & (JC - 1);
                int w = n & (W_IN - 1);
                xv[it] = x[((b * CIN + j0n + j) * H_IN + (h0 + r)) * W_IN + w];
            }
        }
        __syncthreads();   // phi ready
        // ---- GEMM: per s-combo, walk rows r=0..3; A cached across r ----
        const char* cbb  = (const char*)cb + (size_t)(jc * JC * 9) * (COUT * NB * 2);
        const char* ldsb = (const char*)phi_lds;
        const int j0 = jc * JC;
        #pragma unroll
        for (int s = 0; s < 6; ++s) {
            v8s ak[3][4];   // A-frags for k=0,1,2 (filled at r=k, reused at r=k+1)
            #pragma unroll
            for (int r = 0; r < NROWS; ++r) {
                v8s pb = *reinterpret_cast<const v8s*>(ldsb + baddr[s] + r * (RSTRIDE * 2));
                if (r < 3) {
                    #pragma unroll
                    for (int ot = 0; ot < 4; ++ot) {
                        if constexpr (USE_BT) {
                            ak[r][ot] = *reinterpret_cast<const v8s*>(
                                cbb + abase[s] + r * (3 * COUT * NB * 2) + ot * (16 * NB * 2));
                        } else {
                            int c  = s * 4 + g;
                            int jl = c / 3;
                            int lc = c - jl * 3;
                            int o  = ot * 16 + l15;
                            const float* cf = coeff_f +
                                (((o * CIN + (j0 + jl)) * 9 + (r * 3 + lc)) << 3);
                            #pragma unroll
                            for (int z = 0; z < 8; ++z) ak[r][ot][z] = (short)f2bf(cf[z]);
                        }
                        acc0[ot] = __builtin_amdgcn_mfma_f32_16x16x32_bf16(ak[r][ot], pb, acc0[ot], 0, 0, 0);
                    }
                }
                if (r >= 1) {
                    #pragma unroll
                    for (int ot = 0; ot < 4; ++ot) {
                        acc1[ot] = __builtin_amdgcn_mfma_f32_16x16x32_bf16(ak[r - 1][ot], pb, acc1[ot], 0, 0, 0);
                    }
                }
            }
        }
        __syncthreads();   // GEMM done before phi overwrite
    }

    // epilogue: col = l15 = w (coalesced), row o = ot*16 + g*4 + reg
    const int w = wq * 16 + l15;
    if (w < WO) {
        #pragma unroll
        for (int ot = 0; ot < 4; ++ot) {
            int o = ot * 16 + (g << 2);
            #pragma unroll
            for (int r = 0; r < 4; ++r) {
                int base = ((b * COUT + o + r) * HO + h0) * WO + w;
                out[base]      = acc0[ot][r];
                out[base + WO] = acc1[ot][r];
            }
        }
    }
}

extern "C" void kernel_launch(void* const* d_in, const int* in_sizes, int n_in,
                              void* d_out, int out_size, void* d_ws, size_t ws_size,
                              hipStream_t stream) {
    const float* x     = (const float*)d_in[0];
    const float* coeff = (const float*)d_in[1];
    float* out = (float*)d_out;

    const size_t bt_bytes = (size_t)576 * COUT * NB * 2;  // 576 KB
    bool use_bt = ws_size >= bt_bytes;

    if (use_bt) {
        ushort* bt = (ushort*)d_ws;
        prep_coeff_kernel<<<(576 * COUT * NB + 255) / 256, 256, 0, stream>>>(coeff, bt);
        kan_conv_kernel<true><<<dim3(HO / 2, B_N), 256, 0, stream>>>(x, bt, coeff, out);
    } else {
        kan_conv_kernel<false><<<dim3(HO / 2, B_N), 256, 0, stream>>>(x, nullptr, coeff, out);
    }
}

// Round 4
// 69.248 us; speedup vs baseline: 1.0930x; 1.0930x over previous
//
#include <hip/hip_runtime.h>
#include <hip/hip_bf16.h>

// KAN conv: out[b,o,h,w] = sum_{j,k,l,m} phi(x[b,j,h+k,w+l])[m] * coeff[o,j,k,l,m]
// phi = uniform cubic B-spline basis (8 bases, knots = linspace(0,1,12)).
// R4: h-pair blocks (31x16 grid), 4 waves = o-half x w-half (A-dup 2x only).
// r-walk over 4 phi rows serves both output rows; A-frags register-cached.
// phi for chunk jc+1 computed into REGISTERS interleaved with GEMM(jc) MFMAs
// (VALU rides under MFMA); staging critical path = 8 ds_write_b128 + 2 barriers.

typedef short v8s __attribute__((ext_vector_type(8)));
typedef float v4f __attribute__((ext_vector_type(4)));
typedef unsigned long long u64;
typedef u64 v2u64 __attribute__((ext_vector_type(2)));

#define B_N   16
#define CIN   64
#define COUT  64
#define H_IN  64
#define W_IN  64
#define NB    8
#define HO    62
#define WO    62
#define JC    8
#define NCH   (CIN / JC)

__device__ __forceinline__ ushort f2bf(float f) {
    // round-to-nearest-even fp32 -> bf16
    uint xu = __float_as_uint(f);
    return (ushort)((xu + 0x7fffu + ((xu >> 16) & 1u)) >> 16);
}

// Rearrange coeff [o][j][k][l][m] f32 -> bt[t=j*9+k*3+l][o][m] bf16 (576 KB)
__global__ void prep_coeff_kernel(const float* __restrict__ coeff, ushort* __restrict__ bt) {
    int n = blockIdx.x * 256 + threadIdx.x;
    if (n >= 576 * COUT * NB) return;
    int m = n & 7;
    int o = (n >> 3) & 63;
    int t = n >> 9;            // j*9 + k*3 + l
    int j = t / 9;
    int r9 = t - j * 9;
    float v = coeff[(((o * CIN + j) * 9 + r9) << 3) + m];
    bt[n] = f2bf(v);
}

#define MFMA(a, b, c) __builtin_amdgcn_mfma_f32_16x16x32_bf16((a), (b), (c), 0, 0, 0)

__global__ __launch_bounds__(256, 2) void kan_conv_hp(
        const float* __restrict__ x, const ushort* __restrict__ cb,
        float* __restrict__ out) {
    const int h0   = blockIdx.x * 2;   // 0..60
    const int b    = blockIdx.y;
    const int tid  = threadIdx.x;
    const int lane = tid & 63;
    const int wv   = tid >> 6;
    const int oh   = wv >> 1;          // o-half 0/1
    const int wh   = wv & 1;           // w-half 0/1
    const int g    = lane >> 4;
    const int l15  = lane & 15;

    // phi_lds[r(4)][j(8)][w(64)][m(8)] bf16 = 32 KB, single buffer
    __shared__ __align__(16) ushort phi_lds[4 * JC * W_IN * NB];

    // per-lane constant addresses: combo c = s*4+g -> jl=c/3, lc=c%3
    int baddr0[6], baddr1[6], abase[6];
    #pragma unroll
    for (int s = 0; s < 6; ++s) {
        int c  = s * 4 + g;
        int jl = c / 3;
        int lc = c - jl * 3;
        int w0 = wh * 32 + l15 + lc;           // <= 49, never clamps
        int w1 = w0 + 16; w1 = w1 < 63 ? w1 : 63;  // clamped lanes masked at store
        baddr0[s] = jl * 1024 + w0 * 16;
        baddr1[s] = jl * 1024 + w1 * 16;
        abase[s]  = ((jl * 9 + lc) * COUT + oh * 32 + l15) * 16;
    }

    v4f acc[2][2][2];   // [h][ot][wf]
    #pragma unroll
    for (int h = 0; h < 2; ++h)
        #pragma unroll
        for (int ot = 0; ot < 2; ++ot)
            #pragma unroll
            for (int wf = 0; wf < 2; ++wf)
                acc[h][ot][wf] = (v4f){0.f, 0.f, 0.f, 0.f};

    float xreg[8];
    v2u64 phiv[8];

    auto xload = [&](int jcn) {
        int j0n = jcn * JC;
        #pragma unroll
        for (int it = 0; it < 8; ++it) {
            int n = it * 256 + tid;            // n = (r*8 + j)*64 + w
            xreg[it] = x[((b * CIN + j0n + ((n >> 6) & 7)) * H_IN
                          + (h0 + (n >> 9))) * W_IN + (n & 63)];
        }
    };
    auto phiE = [&](int e) {
        float s_ = xreg[e] * 11.0f;
        int i0 = (int)s_;
        i0 = i0 < 0 ? 0 : (i0 > 10 ? 10 : i0);
        float u  = s_ - (float)i0;
        float um = 1.0f - u;
        float u2 = u * u, u3 = u2 * u;
        const float inv6 = 1.0f / 6.0f;
        float n0 = um * um * um * inv6;
        float n1 = (3.0f * u3 - 6.0f * u2 + 4.0f) * inv6;
        float n2 = (-3.0f * u3 + 3.0f * u2 + 3.0f * u + 1.0f) * inv6;
        float n3 = u3 * inv6;
        u64 V = (u64)f2bf(n0) | ((u64)f2bf(n1) << 16)
              | ((u64)f2bf(n2) << 32) | ((u64)f2bf(n3) << 48);
        int bi = i0 - 3;   // first active basis index, in [-3, 7]
        u64 lo = bi < 0 ? (V >> (uint)(-16 * bi))
               : bi < 4 ? (V << (uint)(16 * bi)) : 0ull;
        u64 hi = bi <= 0 ? 0ull
               : bi < 4 ? (V >> (uint)(64 - 16 * bi))
               : (V << (uint)(16 * bi - 64));
        phiv[e][0] = lo; phiv[e][1] = hi;
    };

    // prologue: chunk 0 phi in registers
    xload(0);
    #pragma unroll
    for (int e = 0; e < 8; ++e) phiE(e);

    for (int jc = 0; jc < NCH; ++jc) {
        __syncthreads();   // prior GEMM reads done before overwrite
        #pragma unroll
        for (int it = 0; it < 8; ++it)
            *reinterpret_cast<v2u64*>(&phi_lds[(it * 256 + tid) << 3]) = phiv[it];
        if (jc + 1 < NCH) xload(jc + 1);   // VMEM rides under GEMM
        __syncthreads();   // phi visible
        const char* bb  = (const char*)phi_lds;
        const char* cbb = (const char*)cb + (size_t)jc * (72 * COUT * NB * 2);
        #pragma unroll
        for (int s = 0; s < 6; ++s) {
            // r=0: fill ak0, feed acc0 (h=0,k=0)
            v8s pb0 = *reinterpret_cast<const v8s*>(bb + baddr0[s]);
            v8s pb1 = *reinterpret_cast<const v8s*>(bb + baddr1[s]);
            v8s a00 = *reinterpret_cast<const v8s*>(cbb + abase[s]);
            v8s a01 = *reinterpret_cast<const v8s*>(cbb + abase[s] + 256);
            acc[0][0][0] = MFMA(a00, pb0, acc[0][0][0]);
            acc[0][0][1] = MFMA(a00, pb1, acc[0][0][1]);
            acc[0][1][0] = MFMA(a01, pb0, acc[0][1][0]);
            acc[0][1][1] = MFMA(a01, pb1, acc[0][1][1]);
            // r=1: fill ak1; acc0 gets k=1, acc1 gets k=0
            pb0 = *reinterpret_cast<const v8s*>(bb + 8192 + baddr0[s]);
            pb1 = *reinterpret_cast<const v8s*>(bb + 8192 + baddr1[s]);
            v8s a10 = *reinterpret_cast<const v8s*>(cbb + abase[s] + 3072);
            v8s a11 = *reinterpret_cast<const v8s*>(cbb + abase[s] + 3072 + 256);
            acc[0][0][0] = MFMA(a10, pb0, acc[0][0][0]);
            acc[0][0][1] = MFMA(a10, pb1, acc[0][0][1]);
            acc[0][1][0] = MFMA(a11, pb0, acc[0][1][0]);
            acc[0][1][1] = MFMA(a11, pb1, acc[0][1][1]);
            acc[1][0][0] = MFMA(a00, pb0, acc[1][0][0]);
            acc[1][0][1] = MFMA(a00, pb1, acc[1][0][1]);
            acc[1][1][0] = MFMA(a01, pb0, acc[1][1][0]);
            acc[1][1][1] = MFMA(a01, pb1, acc[1][1][1]);
            // r=2: fill ak2; acc0 gets k=2, acc1 gets k=1
            pb0 = *reinterpret_cast<const v8s*>(bb + 16384 + baddr0[s]);
            pb1 = *reinterpret_cast<const v8s*>(bb + 16384 + baddr1[s]);
            v8s a20 = *reinterpret_cast<const v8s*>(cbb + abase[s] + 6144);
            v8s a21 = *reinterpret_cast<const v8s*>(cbb + abase[s] + 6144 + 256);
            acc[0][0][0] = MFMA(a20, pb0, acc[0][0][0]);
            acc[0][0][1] = MFMA(a20, pb1, acc[0][0][1]);
            acc[0][1][0] = MFMA(a21, pb0, acc[0][1][0]);
            acc[0][1][1] = MFMA(a21, pb1, acc[0][1][1]);
            acc[1][0][0] = MFMA(a10, pb0, acc[1][0][0]);
            acc[1][0][1] = MFMA(a10, pb1, acc[1][0][1]);
            acc[1][1][0] = MFMA(a11, pb0, acc[1][1][0]);
            acc[1][1][1] = MFMA(a11, pb1, acc[1][1][1]);
            // r=3: acc1 gets k=2
            pb0 = *reinterpret_cast<const v8s*>(bb + 24576 + baddr0[s]);
            pb1 = *reinterpret_cast<const v8s*>(bb + 24576 + baddr1[s]);
            acc[1][0][0] = MFMA(a20, pb0, acc[1][0][0]);
            acc[1][0][1] = MFMA(a20, pb1, acc[1][0][1]);
            acc[1][1][0] = MFMA(a21, pb0, acc[1][1][0]);
            acc[1][1][1] = MFMA(a21, pb1, acc[1][1][1]);
            // interleave next chunk's phi VALU under the MFMA stream
            if (s < 4 && jc + 1 < NCH) { phiE(2 * s); phiE(2 * s + 1); }
        }
    }

    // epilogue: col = l15 = w (coalesced), row o = oh*32 + ot*16 + g*4 + r
    const int w0c = wh * 32 + l15;
    const int w1c = w0c + 16;
    #pragma unroll
    for (int h = 0; h < 2; ++h)
        #pragma unroll
        for (int ot = 0; ot < 2; ++ot) {
            int o = oh * 32 + ot * 16 + (g << 2);
            #pragma unroll
            for (int r = 0; r < 4; ++r) {
                int base = ((b * COUT + o + r) * HO + (h0 + h)) * WO;
                if (w0c < WO) out[base + w0c] = acc[h][ot][0][r];
                if (w1c < WO) out[base + w1c] = acc[h][ot][1][r];
            }
        }
}

// ---- fallback (ws too small for bt): R2-proven kernel, coeff from f32 ----
__global__ __launch_bounds__(256, 4) void kan_conv_fb(
        const float* __restrict__ x, const float* __restrict__ coeff_f,
        float* __restrict__ out) {
    const int h    = blockIdx.x;
    const int b    = blockIdx.y;
    const int tid  = threadIdx.x;
    const int lane = tid & 63;
    const int wv   = tid >> 6;
    const int g    = lane >> 4;
    const int l15  = lane & 15;
    const int obase = (wv >> 1) << 5;
    const int wbase = (wv & 1) << 5;

    __shared__ __align__(16) ushort phi_lds[3 * JC * W_IN * NB];
    __shared__ uint lut[72];
    if (tid < 72) {
        int tap = tid;
        int j  = tap / 9;
        int r9 = tap - j * 9;
        int kt = r9 / 3;
        int lt = r9 - kt * 3;
        lut[tap] = (uint)(((kt * JC + j) * W_IN) * NB) | ((uint)lt << 16)
                 | ((uint)j << 20) | ((uint)r9 << 24);
    }
    v4f acc00 = {0.f, 0.f, 0.f, 0.f};
    v4f acc01 = acc00, acc10 = acc00, acc11 = acc00;
    const int aoff = obase + l15;
    float xv[6];
    #pragma unroll
    for (int it = 0; it < 6; ++it) {
        int n = it * 256 + tid;
        xv[it] = x[((b * CIN + ((n >> 6) & 7)) * H_IN + (h + (n >> 9))) * W_IN + (n & 63)];
    }
    for (int jc = 0; jc < NCH; ++jc) {
        #pragma unroll
        for (int it = 0; it < 6; ++it) {
            int n = it * 256 + tid;
            float s  = xv[it] * 11.0f;
            int i0 = (int)s;
            i0 = i0 < 0 ? 0 : (i0 > 10 ? 10 : i0);
            float u  = s - (float)i0;
            float um = 1.0f - u;
            float u2 = u * u, u3 = u2 * u;
            const float inv6 = 1.0f / 6.0f;
            float n0 = um * um * um * inv6;
            float n1 = (3.0f * u3 - 6.0f * u2 + 4.0f) * inv6;
            float n2 = (-3.0f * u3 + 3.0f * u2 + 3.0f * u + 1.0f) * inv6;
            float n3 = u3 * inv6;
            u64 V = (u64)f2bf(n0) | ((u64)f2bf(n1) << 16)
                  | ((u64)f2bf(n2) << 32) | ((u64)f2bf(n3) << 48);
            int bi = i0 - 3;
            u64 lo = bi < 0 ? (V >> (uint)(-16 * bi))
                   : bi < 4 ? (V << (uint)(16 * bi)) : 0ull;
            u64 hi = bi <= 0 ? 0ull
                   : bi < 4 ? (V >> (uint)(64 - 16 * bi))
                   : (V << (uint)(16 * bi - 64));
            v2u64 pk; pk[0] = lo; pk[1] = hi;
            *reinterpret_cast<v2u64*>(&phi_lds[n << 3]) = pk;
        }
        if (jc + 1 < NCH) {
            int j0n = (jc + 1) * JC;
            #pragma unroll
            for (int it = 0; it < 6; ++it) {
                int n = it * 256 + tid;
                xv[it] = x[((b * CIN + j0n + ((n >> 6) & 7)) * H_IN + (h + (n >> 9))) * W_IN + (n & 63)];
            }
        }
        __syncthreads();
        const int j0 = jc * JC;
        #pragma unroll 6
        for (int kk = 0; kk < 18; ++kk) {
            int tap = (kk << 2) + g;
            uint e = lut[tap];
            int philoc = (int)(e & 0xffffu);
            int lt     = (int)((e >> 16) & 3u);
            int w0 = wbase + l15 + lt;
            int w1 = w0 + 16;
            w0 = w0 < 63 ? w0 : 63;
            w1 = w1 < 63 ? w1 : 63;
            v8s pb0 = *reinterpret_cast<const v8s*>(&phi_lds[philoc + (w0 << 3)]);
            v8s pb1 = *reinterpret_cast<const v8s*>(&phi_lds[philoc + (w1 << 3)]);
            int j  = (int)((e >> 20) & 15u);
            int r9 = (int)((e >> 24) & 15u);
            const float* cf = coeff_f + (((aoff * CIN + (j0 + j)) * 9 + r9) << 3);
            v8s pa0, pa1;
            #pragma unroll
            for (int z = 0; z < 8; ++z) pa0[z] = (short)f2bf(cf[z]);
            const float* cf2 = cf + (CIN * 9 * NB * 16);
            #pragma unroll
            for (int z = 0; z < 8; ++z) pa1[z] = (short)f2bf(cf2[z]);
            acc00 = MFMA(pa0, pb0, acc00);
            acc01 = MFMA(pa0, pb1, acc01);
            acc10 = MFMA(pa1, pb0, acc10);
            acc11 = MFMA(pa1, pb1, acc11);
        }
        __syncthreads();
    }
    const int wc0 = wbase + l15;
    const int wc1 = wc0 + 16;
    #pragma unroll
    for (int i = 0; i < 2; ++i) {
        v4f a0 = (i == 0) ? acc00 : acc10;
        v4f a1 = (i == 0) ? acc01 : acc11;
        int o = obase + i * 16 + (g << 2);
        #pragma unroll
        for (int r = 0; r < 4; ++r) {
            int off = ((b * COUT + o + r) * HO + h) * WO;
            if (wc0 < WO) out[off + wc0] = a0[r];
            if (wc1 < WO) out[off + wc1] = a1[r];
        }
    }
}

extern "C" void kernel_launch(void* const* d_in, const int* in_sizes, int n_in,
                              void* d_out, int out_size, void* d_ws, size_t ws_size,
                              hipStream_t stream) {
    const float* x     = (const float*)d_in[0];
    const float* coeff = (const float*)d_in[1];
    float* out = (float*)d_out;

    const size_t bt_bytes = (size_t)576 * COUT * NB * 2;  // 576 KB
    if (ws_size >= bt_bytes) {
        ushort* bt = (ushort*)d_ws;
        prep_coeff_kernel<<<(576 * COUT * NB + 255) / 256, 256, 0, stream>>>(coeff, bt);
        kan_conv_hp<<<dim3(HO / 2, B_N), 256, 0, stream>>>(x, bt, out);
    } else {
        kan_conv_fb<<<dim3(HO, B_N), 256, 0, stream>>>(x, coeff, out);
    }
}

// Round 5
// 56.177 us; speedup vs baseline: 1.3473x; 1.2327x over previous
//
#include <hip/hip_runtime.h>
#include <hip/hip_bf16.h>

// KAN conv: out[b,o,h,w] = sum_{j,k,l,m} phi(x[b,j,h+k,w+l])[m] * coeff[o,j,k,l,m]
// phi = uniform cubic B-spline basis (8 bases, knots = linspace(0,1,12)).
// R5: block=(b,h) (992 blocks, 4/CU). Waves split K: wave kh owns j-pair jp=kh,
// all waves accumulate partials for the FULL 64o x 64w tile via 32x32x16 MFMA
// (B-frag feeds 2 MFMA at 2x FLOP -> LDS-read pipe off critical path; A read
// exactly once per block). K-order chosen so B ds_reads use compile-time
// immediates and A-loads are pointer+const. Epilogue: LDS tree-reduce.

typedef short v8s __attribute__((ext_vector_type(8)));
typedef float v4f __attribute__((ext_vector_type(4)));
typedef float v16f __attribute__((ext_vector_type(16)));
typedef unsigned long long u64;
typedef u64 v2u64 __attribute__((ext_vector_type(2)));

#define B_N   16
#define CIN   64
#define COUT  64
#define H_IN  64
#define W_IN  64
#define NB    8
#define HO    62
#define WO    62
#define JC    8
#define NCH   8

__device__ __forceinline__ ushort f2bf(float f) {
    // round-to-nearest-even fp32 -> bf16
    uint xu = __float_as_uint(f);
    return (ushort)((xu + 0x7fffu + ((xu >> 16) & 1u)) >> 16);
}

// bt layout: [jc(8)][tap(9)][jp(4)][o(64)][g2(2)][m(8)] bf16, 576 KB.
// j_global = jc*8 + jp*2 + g2; tap = k*3+l.
__global__ void prep_coeff_kernel(const float* __restrict__ coeff, ushort* __restrict__ bt) {
    int n = blockIdx.x * 256 + threadIdx.x;   // 294912 total
    if (n >= 294912) return;
    int m  = n & 7;
    int g2 = (n >> 3) & 1;
    int o  = (n >> 4) & 63;
    int jp = (n >> 10) & 3;
    int q  = n >> 12;          // 0..71
    int tap = q % 9;
    int jc  = q / 9;
    int j = jc * 8 + jp * 2 + g2;
    bt[n] = f2bf(coeff[((o * CIN + j) * 9 + tap) * 8 + m]);
}

#define MFMA32(a, b, c) __builtin_amdgcn_mfma_f32_32x32x16_bf16((a), (b), (c), 0, 0, 0)
#define MFMA16(a, b, c) __builtin_amdgcn_mfma_f32_16x16x32_bf16((a), (b), (c), 0, 0, 0)

__global__ __launch_bounds__(256, 4) void kan_conv_ks(
        const float* __restrict__ x, const ushort* __restrict__ cb,
        float* __restrict__ out) {
    const int h    = blockIdx.x;      // 0..61
    const int b    = blockIdx.y;
    const int tid  = threadIdx.x;
    const int lane = tid & 63;
    const int kh   = tid >> 6;        // wave id = K-split (jp = kh)
    const int l31  = lane & 31;
    const int g2   = lane >> 5;

    // union: phi[k(3)][j(8)][w(64)][m(8)] bf16 (24 KB + slack) | reduce buf 32 KB
    __shared__ __align__(16) char smraw[32768];
    ushort* phi = (ushort*)smraw;

    // acc[ot][wf]: 4 tiles of 32x32, 16 f32 each (full 64o x 64w partial)
    v16f acc[2][2];
    #pragma unroll
    for (int t = 0; t < 2; ++t) {
        acc[t][0] = (v16f)(0.f);
        acc[t][1] = (v16f)(0.f);
    }

    float xreg[6];
    auto xload = [&](int jcn) {
        #pragma unroll
        for (int it = 0; it < 6; ++it) {
            int n = it * 256 + tid;            // n = (k*8 + j)*64 + w
            xreg[it] = x[((b * CIN + jcn * 8 + ((n >> 6) & 7)) * H_IN
                          + (h + (n >> 9))) * W_IN + (n & 63)];
        }
    };
    xload(0);

    // per-lane constant bases
    const char* pBbase = smraw + (kh * 2 + g2) * 1024 + l31 * 16;
    const v8s*  cbv    = reinterpret_cast<const v8s*>(cb) + kh * 128 + l31 * 2 + g2;

    for (int jc = 0; jc < NCH; ++jc) {
        // ---- stage phi: compute + single 16B LDS write per element ----
        #pragma unroll
        for (int it = 0; it < 6; ++it) {
            int n = it * 256 + tid;
            float s_ = xreg[it] * 11.0f;
            int i0 = (int)s_;
            i0 = i0 < 0 ? 0 : (i0 > 10 ? 10 : i0);
            float u  = s_ - (float)i0;
            float um = 1.0f - u;
            float u2 = u * u, u3 = u2 * u;
            const float inv6 = 1.0f / 6.0f;
            float n0 = um * um * um * inv6;
            float n1 = (3.0f * u3 - 6.0f * u2 + 4.0f) * inv6;
            float n2 = (-3.0f * u3 + 3.0f * u2 + 3.0f * u + 1.0f) * inv6;
            float n3 = u3 * inv6;
            u64 V = (u64)f2bf(n0) | ((u64)f2bf(n1) << 16)
                  | ((u64)f2bf(n2) << 32) | ((u64)f2bf(n3) << 48);
            int bi = i0 - 3;   // first active basis index, in [-3, 7]
            u64 lo = bi < 0 ? (V >> (uint)(-16 * bi))
                   : bi < 4 ? (V << (uint)(16 * bi)) : 0ull;
            u64 hi = bi <= 0 ? 0ull
                   : bi < 4 ? (V >> (uint)(64 - 16 * bi))
                   : (V << (uint)(16 * bi - 64));
            v2u64 pk; pk[0] = lo; pk[1] = hi;
            *reinterpret_cast<v2u64*>(&phi[n << 3]) = pk;
        }
        if (jc + 1 < NCH) xload(jc + 1);   // VMEM rides under GEMM
        __syncthreads();   // phi visible

        // ---- GEMM: 9 taps, each: 2 A-loads, 2 B-reads (imm offsets), 4 MFMA ----
        const v8s* pAc = cbv + jc * 4608;
        #pragma unroll
        for (int tap = 0; tap < 9; ++tap) {
            const int k  = tap / 3;
            const int lt = tap - k * 3;
            v8s a0 = pAc[tap * 512];
            v8s a1 = pAc[tap * 512 + 64];
            v8s b0 = *reinterpret_cast<const v8s*>(pBbase + k * 8192 + lt * 16);
            v8s b1 = *reinterpret_cast<const v8s*>(pBbase + k * 8192 + lt * 16 + 512);
            acc[0][0] = MFMA32(a0, b0, acc[0][0]);
            acc[0][1] = MFMA32(a0, b1, acc[0][1]);
            acc[1][0] = MFMA32(a1, b0, acc[1][0]);
            acc[1][1] = MFMA32(a1, b1, acc[1][1]);
        }
        __syncthreads();   // GEMM reads done before overwrite / epilogue
    }

    // ---- cross-wave K-reduce via LDS tree, wave 0 stores ----
    float* red = (float*)smraw;
    auto wr_acc = [&](int slot) {
        #pragma unroll
        for (int t = 0; t < 4; ++t)
            #pragma unroll
            for (int q = 0; q < 4; ++q) {
                v4f v;
                #pragma unroll
                for (int z = 0; z < 4; ++z) v[z] = acc[t >> 1][t & 1][q * 4 + z];
                *reinterpret_cast<v4f*>(smraw + slot * 16384 + (t * 4 + q) * 1024 + lane * 16) = v;
            }
    };
    auto add_acc = [&](int slot) {
        #pragma unroll
        for (int t = 0; t < 4; ++t)
            #pragma unroll
            for (int q = 0; q < 4; ++q) {
                v4f v = *reinterpret_cast<const v4f*>(smraw + slot * 16384 + (t * 4 + q) * 1024 + lane * 16);
                #pragma unroll
                for (int z = 0; z < 4; ++z) acc[t >> 1][t & 1][q * 4 + z] += v[z];
            }
    };
    if (kh == 1) wr_acc(0);
    if (kh == 3) wr_acc(1);
    __syncthreads();
    if (kh == 0) add_acc(0);
    if (kh == 2) add_acc(1);
    __syncthreads();
    if (kh == 2) wr_acc(0);
    __syncthreads();
    if (kh == 0) {
        add_acc(0);
        // store: col = l31 -> w = wf*32+l31; row o = ot*32 + (reg&3)+8*(reg>>2)+4*g2
        #pragma unroll
        for (int ot = 0; ot < 2; ++ot)
            #pragma unroll
            for (int wf = 0; wf < 2; ++wf) {
                int w = wf * 32 + l31;
                if (w < WO) {
                    #pragma unroll
                    for (int reg = 0; reg < 16; ++reg) {
                        int o = ot * 32 + (reg & 3) + 8 * (reg >> 2) + 4 * g2;
                        out[((b * COUT + o) * HO + h) * WO + w] = acc[ot][wf][reg];
                    }
                }
            }
    }
    (void)red;
}

// ---- fallback (ws too small for bt): R2-proven kernel, coeff from f32 ----
__global__ __launch_bounds__(256, 4) void kan_conv_fb(
        const float* __restrict__ x, const float* __restrict__ coeff_f,
        float* __restrict__ out) {
    const int h    = blockIdx.x;
    const int b    = blockIdx.y;
    const int tid  = threadIdx.x;
    const int lane = tid & 63;
    const int wv   = tid >> 6;
    const int g    = lane >> 4;
    const int l15  = lane & 15;
    const int obase = (wv >> 1) << 5;
    const int wbase = (wv & 1) << 5;

    __shared__ __align__(16) ushort phi_lds[3 * JC * W_IN * NB];
    __shared__ uint lut[72];
    if (tid < 72) {
        int tap = tid;
        int j  = tap / 9;
        int r9 = tap - j * 9;
        int kt = r9 / 3;
        int lt = r9 - kt * 3;
        lut[tap] = (uint)(((kt * JC + j) * W_IN) * NB) | ((uint)lt << 16)
                 | ((uint)j << 20) | ((uint)r9 << 24);
    }
    v4f acc00 = {0.f, 0.f, 0.f, 0.f};
    v4f acc01 = acc00, acc10 = acc00, acc11 = acc00;
    const int aoff = obase + l15;
    float xv[6];
    #pragma unroll
    for (int it = 0; it < 6; ++it) {
        int n = it * 256 + tid;
        xv[it] = x[((b * CIN + ((n >> 6) & 7)) * H_IN + (h + (n >> 9))) * W_IN + (n & 63)];
    }
    for (int jc = 0; jc < NCH; ++jc) {
        #pragma unroll
        for (int it = 0; it < 6; ++it) {
            int n = it * 256 + tid;
            float s  = xv[it] * 11.0f;
            int i0 = (int)s;
            i0 = i0 < 0 ? 0 : (i0 > 10 ? 10 : i0);
            float u  = s - (float)i0;
            float um = 1.0f - u;
            float u2 = u * u, u3 = u2 * u;
            const float inv6 = 1.0f / 6.0f;
            float n0 = um * um * um * inv6;
            float n1 = (3.0f * u3 - 6.0f * u2 + 4.0f) * inv6;
            float n2 = (-3.0f * u3 + 3.0f * u2 + 3.0f * u + 1.0f) * inv6;
            float n3 = u3 * inv6;
            u64 V = (u64)f2bf(n0) | ((u64)f2bf(n1) << 16)
                  | ((u64)f2bf(n2) << 32) | ((u64)f2bf(n3) << 48);
            int bi = i0 - 3;
            u64 lo = bi < 0 ? (V >> (uint)(-16 * bi))
                   : bi < 4 ? (V << (uint)(16 * bi)) : 0ull;
            u64 hi = bi <= 0 ? 0ull
                   : bi < 4 ? (V >> (uint)(64 - 16 * bi))
                   : (V << (uint)(16 * bi - 64));
            v2u64 pk; pk[0] = lo; pk[1] = hi;
            *reinterpret_cast<v2u64*>(&phi_lds[n << 3]) = pk;
        }
        if (jc + 1 < NCH) {
            int j0n = (jc + 1) * JC;
            #pragma unroll
            for (int it = 0; it < 6; ++it) {
                int n = it * 256 + tid;
                xv[it] = x[((b * CIN + j0n + ((n >> 6) & 7)) * H_IN + (h + (n >> 9))) * W_IN + (n & 63)];
            }
        }
        __syncthreads();
        const int j0 = jc * JC;
        #pragma unroll 6
        for (int kk = 0; kk < 18; ++kk) {
            int tap = (kk << 2) + g;
            uint e = lut[tap];
            int philoc = (int)(e & 0xffffu);
            int lt     = (int)((e >> 16) & 3u);
            int w0 = wbase + l15 + lt;
            int w1 = w0 + 16;
            w0 = w0 < 63 ? w0 : 63;
            w1 = w1 < 63 ? w1 : 63;
            v8s pb0 = *reinterpret_cast<const v8s*>(&phi_lds[philoc + (w0 << 3)]);
            v8s pb1 = *reinterpret_cast<const v8s*>(&phi_lds[philoc + (w1 << 3)]);
            int j  = (int)((e >> 20) & 15u);
            int r9 = (int)((e >> 24) & 15u);
            const float* cf = coeff_f + (((aoff * CIN + (j0 + j)) * 9 + r9) << 3);
            v8s pa0, pa1;
            #pragma unroll
            for (int z = 0; z < 8; ++z) pa0[z] = (short)f2bf(cf[z]);
            const float* cf2 = cf + (CIN * 9 * NB * 16);
            #pragma unroll
            for (int z = 0; z < 8; ++z) pa1[z] = (short)f2bf(cf2[z]);
            acc00 = MFMA16(pa0, pb0, acc00);
            acc01 = MFMA16(pa0, pb1, acc01);
            acc10 = MFMA16(pa1, pb0, acc10);
            acc11 = MFMA16(pa1, pb1, acc11);
        }
        __syncthreads();
    }
    const int wc0 = wbase + l15;
    const int wc1 = wc0 + 16;
    #pragma unroll
    for (int i = 0; i < 2; ++i) {
        v4f a0 = (i == 0) ? acc00 : acc10;
        v4f a1 = (i == 0) ? acc01 : acc11;
        int o = obase + i * 16 + (g << 2);
        #pragma unroll
        for (int r = 0; r < 4; ++r) {
            int off = ((b * COUT + o + r) * HO + h) * WO;
            if (wc0 < WO) out[off + wc0] = a0[r];
            if (wc1 < WO) out[off + wc1] = a1[r];
        }
    }
}

extern "C" void kernel_launch(void* const* d_in, const int* in_sizes, int n_in,
                              void* d_out, int out_size, void* d_ws, size_t ws_size,
                              hipStream_t stream) {
    const float* x     = (const float*)d_in[0];
    const float* coeff = (const float*)d_in[1];
    float* out = (float*)d_out;

    const size_t bt_bytes = (size_t)294912 * 2;  // 576 KB
    if (ws_size >= bt_bytes) {
        ushort* bt = (ushort*)d_ws;
        prep_coeff_kernel<<<(294912 + 255) / 256, 256, 0, stream>>>(coeff, bt);
        kan_conv_ks<<<dim3(HO, B_N), 256, 0, stream>>>(x, bt, out);
    } else {
        kan_conv_fb<<<dim3(HO, B_N), 256, 0, stream>>>(x, coeff, out);
    }
}